// Round 1
// baseline (7876.118 us; speedup 1.0000x reference)
//
#include <hip/hip_runtime.h>
#include <hip/hip_bf16.h>

#define DEV __device__ __forceinline__

constexpr int B = 64, S = 128, T = 32, H = 1024, V = 32000;
constexpr int H4 = 4096;          // 4*H
constexpr int KX = 3072;          // [emb | ctx | h] concat length
constexpr int NB_LOGITS = V / 64; // 500 blocks for the logits GEMM

using f32x4   = __attribute__((ext_vector_type(4))) float;
using short8v = __attribute__((ext_vector_type(8))) short;

DEV unsigned short f2bf(float x) {
  union { __hip_bfloat16 b; unsigned short u; } v;
  v.b = __float2bfloat16(x);
  return v.u;
}

DEV float fast_sig(float x) { return 1.0f / (1.0f + __expf(-x)); }
DEV float fast_tanh(float x) {
  float e = __expf(2.0f * x);
  return 1.0f - 2.0f / (e + 1.0f);
}

// f32 -> bf16 bulk convert (weights), n multiple of 8
__global__ __launch_bounds__(256) void k_f32_to_bf16(
    const float* __restrict__ src, unsigned short* __restrict__ dst, int n) {
  int i0 = (blockIdx.x * 256 + threadIdx.x) * 8;
  int stride = gridDim.x * 256 * 8;
  for (int i = i0; i < n; i += stride) {
    float4 a = *(const float4*)(src + i);
    float4 c = *(const float4*)(src + i + 4);
    ushort4 u1, u2;
    u1.x = f2bf(a.x); u1.y = f2bf(a.y); u1.z = f2bf(a.z); u1.w = f2bf(a.w);
    u2.x = f2bf(c.x); u2.y = f2bf(c.y); u2.z = f2bf(c.z); u2.w = f2bf(c.w);
    *(ushort4*)(dst + i)     = u1;
    *(ushort4*)(dst + i + 4) = u2;
  }
}

// Generic M=64 GEMM: C[b,n] = bias1[n]+bias2[n] + sum_k A[b,k] * W[n,k]
// W is split at k=ksplit between Wa (stride ldwa) and Wb (stride ldwb).
// W arrays are bf16 if wbf16 else f32 (converted during staging).
// If pm/pl nonnull, also emit per-(block,b) softmax partials (max, sumexp).
// grid.x = N/64, 256 threads. MFMA 16x16x32 bf16, fragment-shuffled LDS:
//   slab (16 rows x 32 k) stored so lane l reads its 16B fragment at l*16B.
__global__ __launch_bounds__(256) void gemm64_mfma(
    const float* __restrict__ A, int lda,
    const void* __restrict__ Wa, int ldwa,
    const void* __restrict__ Wb, int ldwb, int ksplit,
    const float* __restrict__ bias1, const float* __restrict__ bias2,
    float* __restrict__ C, size_t ldc,
    int K, int wbf16,
    float* __restrict__ pm, float* __restrict__ pl)
{
  __shared__ unsigned short As[2048]; // 64m x 32k bf16
  __shared__ unsigned short Bs[2048]; // 64n x 32k bf16
  __shared__ float Pm[4][64];
  __shared__ float Pl[4][64];

  const int tid  = threadIdx.x;
  const int lane = tid & 63;
  const int w    = tid >> 6;
  const int n0   = blockIdx.x * 64;

  f32x4 acc0 = {0.f,0.f,0.f,0.f}, acc1 = {0.f,0.f,0.f,0.f};
  f32x4 acc2 = {0.f,0.f,0.f,0.f}, acc3 = {0.f,0.f,0.f,0.f};

  for (int k0 = 0; k0 < K; k0 += 32) {
    #pragma unroll
    for (int ss = 0; ss < 2; ++ss) {
      int s  = tid + ss * 256;  // 0..511
      int r  = s >> 3;          // tile row 0..63
      int kq = s & 7;           // k-quad
      int kL = kq * 4;
      int kg = k0 + kL;
      // A side: f32 -> bf16
      const float* ap = A + (size_t)r * lda + kg;
      float4 av = *(const float4*)ap;
      ushort4 au;
      au.x = f2bf(av.x); au.y = f2bf(av.y); au.z = f2bf(av.z); au.w = f2bf(av.w);
      int dst = ((r >> 4) << 9) + ((kL >> 3) << 7) + ((r & 15) << 3) + (kL & 7);
      *(ushort4*)&As[dst] = au;
      // B side: row n0+r of W (transposed into B[k][n])
      int n = n0 + r;
      ushort4 bu;
      if (wbf16) {
        const unsigned short* wp = (kg < ksplit)
          ? (const unsigned short*)Wa + (size_t)n * ldwa + kg
          : (const unsigned short*)Wb + (size_t)n * ldwb + (kg - ksplit);
        bu = *(const ushort4*)wp;
      } else {
        const float* wp = (kg < ksplit)
          ? (const float*)Wa + (size_t)n * ldwa + kg
          : (const float*)Wb + (size_t)n * ldwb + (kg - ksplit);
        float4 wv = *(const float4*)wp;
        bu.x = f2bf(wv.x); bu.y = f2bf(wv.y); bu.z = f2bf(wv.z); bu.w = f2bf(wv.w);
      }
      *(ushort4*)&Bs[dst] = bu;
    }
    __syncthreads();
    short8v bf = *(const short8v*)&Bs[(w << 9) + (lane << 3)];
    short8v a0 = *(const short8v*)&As[(0 << 9) + (lane << 3)];
    short8v a1 = *(const short8v*)&As[(1 << 9) + (lane << 3)];
    short8v a2 = *(const short8v*)&As[(2 << 9) + (lane << 3)];
    short8v a3 = *(const short8v*)&As[(3 << 9) + (lane << 3)];
    acc0 = __builtin_amdgcn_mfma_f32_16x16x32_bf16(a0, bf, acc0, 0, 0, 0);
    acc1 = __builtin_amdgcn_mfma_f32_16x16x32_bf16(a1, bf, acc1, 0, 0, 0);
    acc2 = __builtin_amdgcn_mfma_f32_16x16x32_bf16(a2, bf, acc2, 0, 0, 0);
    acc3 = __builtin_amdgcn_mfma_f32_16x16x32_bf16(a3, bf, acc3, 0, 0, 0);
    __syncthreads();
  }

  // epilogue: C/D frag mapping col = lane&15, row = (lane>>4)*4 + r (+16*mb)
  const int col = n0 + (w << 4) + (lane & 15);
  const float bv = (bias1 ? bias1[col] : 0.0f) + (bias2 ? bias2[col] : 0.0f);
  f32x4 accs[4] = {acc0, acc1, acc2, acc3};
  float vals[4][4];
  #pragma unroll
  for (int mb = 0; mb < 4; ++mb) {
    #pragma unroll
    for (int r = 0; r < 4; ++r) {
      int row = (mb << 4) + ((lane >> 4) << 2) + r;
      float v = accs[mb][r] + bv;
      vals[mb][r] = v;
      C[(size_t)row * ldc + col] = v;
    }
  }

  if (pm) {
    #pragma unroll
    for (int mb = 0; mb < 4; ++mb) {
      #pragma unroll
      for (int r = 0; r < 4; ++r) {
        float v = vals[mb][r];
        float m = v;
        #pragma unroll
        for (int d = 1; d < 16; d <<= 1) m = fmaxf(m, __shfl_xor(m, d));
        float e = __expf(v - m);
        #pragma unroll
        for (int d = 1; d < 16; d <<= 1) e += __shfl_xor(e, d);
        if ((lane & 15) == 0) {
          int row = (mb << 4) + ((lane >> 4) << 2) + r;
          Pm[w][row] = m;
          Pl[w][row] = e;
        }
      }
    }
    __syncthreads();
    if (tid < 64) {
      float M = Pm[0][tid];
      M = fmaxf(M, Pm[1][tid]); M = fmaxf(M, Pm[2][tid]); M = fmaxf(M, Pm[3][tid]);
      float L = Pl[0][tid] * __expf(Pm[0][tid] - M)
              + Pl[1][tid] * __expf(Pm[1][tid] - M)
              + Pl[2][tid] * __expf(Pm[2][tid] - M)
              + Pl[3][tid] * __expf(Pm[3][tid] - M);
      pm[(size_t)blockIdx.x * 64 + tid] = M;
      pl[(size_t)blockIdx.x * 64 + tid] = L;
    }
  }
}

// scores[b,s] = Vb + sum_h Vw[h] * tanh(qW1[b,h] + keys[s,h])
// grid = B*4 (b x s-quarter), 256 threads (4 waves x 8 s each)
__global__ __launch_bounds__(256) void k_scores(
    const float* __restrict__ qW1, const float* __restrict__ keys,
    const float* __restrict__ Vw, const float* __restrict__ Vb,
    float* __restrict__ scores)
{
  __shared__ float qw[H];
  __shared__ float vw[H];
  const int b  = blockIdx.x >> 2;
  const int sq = blockIdx.x & 3;
  const int tid = threadIdx.x;
  #pragma unroll
  for (int i = 0; i < 4; ++i) {
    qw[tid + i * 256] = qW1[b * H + tid + i * 256];
    vw[tid + i * 256] = Vw[tid + i * 256];
  }
  __syncthreads();
  const int w = tid >> 6, lane = tid & 63;
  #pragma unroll
  for (int si = 0; si < 8; ++si) {
    int sg = sq * 32 + w * 8 + si;
    const float* kp = keys + (size_t)sg * H;
    float p = 0.0f;
    #pragma unroll
    for (int u = 0; u < 16; ++u) {
      int h = lane + (u << 6);
      p += vw[h] * fast_tanh(qw[h] + kp[h]);
    }
    #pragma unroll
    for (int d = 1; d < 64; d <<= 1) p += __shfl_xor(p, d);
    if (lane == 0) scores[b * S + sg] = p + Vb[0];
  }
}

// softmax over S, context, attn write, xbuf = [emb[tok] | ctx | h]
// grid = B*4 (b x h-quarter), 256 threads
__global__ __launch_bounds__(256) void k_attn_ctx(
    const float* __restrict__ scores, const float* __restrict__ enc,
    const float* __restrict__ emb, const int* __restrict__ tok,
    const float* __restrict__ hcur, float* __restrict__ xbuf,
    float* __restrict__ attn_out, int t)
{
  __shared__ float al[S];
  __shared__ float wred[4];
  const int b   = blockIdx.x >> 2;
  const int hq  = blockIdx.x & 3;
  const int tid = threadIdx.x;

  float sv = (tid < S) ? scores[b * S + tid] : -1e30f;
  float m = sv;
  #pragma unroll
  for (int d = 1; d < 64; d <<= 1) m = fmaxf(m, __shfl_xor(m, d));
  if ((tid & 63) == 0) wred[tid >> 6] = m;
  __syncthreads();
  m = fmaxf(fmaxf(wred[0], wred[1]), fmaxf(wred[2], wred[3]));
  float e = (tid < S) ? __expf(sv - m) : 0.0f;
  float ssum = e;
  #pragma unroll
  for (int d = 1; d < 64; d <<= 1) ssum += __shfl_xor(ssum, d);
  __syncthreads();   // wred reads done
  if ((tid & 63) == 0) wred[tid >> 6] = ssum;
  __syncthreads();
  float tot = wred[0] + wred[1] + wred[2] + wred[3];
  float a = e / tot;
  if (tid < S) {
    al[tid] = a;
    if (hq == 0) attn_out[((size_t)t * B + b) * S + tid] = a;
  }
  __syncthreads();

  const int h = hq * 256 + tid;
  float acc = 0.0f;
  const float* ep = enc + (size_t)b * S * H + h;
  #pragma unroll 4
  for (int s = 0; s < S; ++s) acc += al[s] * ep[(size_t)s * H];

  int token = tok[b * T + t];
  xbuf[b * KX + h]         = emb[(size_t)token * H + h];
  xbuf[b * KX + H + h]     = acc;
  xbuf[b * KX + 2 * H + h] = hcur[b * H + h];
}

// LSTM cell update. grid = B*H/256
__global__ __launch_bounds__(256) void k_cell(
    const float* __restrict__ gates, const float* __restrict__ cprev,
    float* __restrict__ hnew, float* __restrict__ cnew,
    float* __restrict__ hout, float* __restrict__ cout, int last)
{
  int idx = blockIdx.x * 256 + threadIdx.x;   // b*H + h
  int b = idx >> 10, h = idx & 1023;
  const float* g = gates + (size_t)b * H4;
  float gi = g[h], gf = g[H + h], gg = g[2 * H + h], go = g[3 * H + h];
  float c = fast_sig(gf) * cprev[idx] + fast_sig(gi) * fast_tanh(gg);
  float hv = fast_sig(go) * fast_tanh(c);
  cnew[idx] = c;
  hnew[idx] = hv;
  if (last) { hout[idx] = hv; cout[idx] = c; }
}

// log-softmax normalize: reduce 500 (m,l) partials per b, subtract logZ.
// grid = B*125, 256 threads; chunk = 256 v per block
__global__ __launch_bounds__(256) void k_norm(
    const float* __restrict__ pm, const float* __restrict__ pl,
    float* __restrict__ lp, int t)
{
  __shared__ float rm[256], rl[256];
  const int bx = blockIdx.x;
  const int b  = bx / 125;
  const int ch = bx % 125;
  const int tid = threadIdx.x;

  float m1 = pm[(size_t)tid * 64 + b];
  float l1 = pl[(size_t)tid * 64 + b];
  int nb2 = tid + 256;
  if (nb2 < NB_LOGITS) {
    float m2 = pm[(size_t)nb2 * 64 + b];
    float l2 = pl[(size_t)nb2 * 64 + b];
    float M = fmaxf(m1, m2);
    l1 = l1 * __expf(m1 - M) + l2 * __expf(m2 - M);
    m1 = M;
  }
  rm[tid] = m1; rl[tid] = l1;
  __syncthreads();
  for (int off = 128; off > 0; off >>= 1) {
    if (tid < off) {
      float ma = rm[tid], mb = rm[tid + off];
      float M = fmaxf(ma, mb);
      rl[tid] = rl[tid] * __expf(ma - M) + rl[tid + off] * __expf(mb - M);
      rm[tid] = M;
    }
    __syncthreads();
  }
  float logZ = rm[0] + __logf(rl[0]);
  size_t base = ((size_t)b * T + t) * V + (size_t)ch * 256;
  lp[base + tid] -= logZ;
}

extern "C" void kernel_launch(void* const* d_in, const int* in_sizes, int n_in,
                              void* d_out, int out_size, void* d_ws, size_t ws_size,
                              hipStream_t stream)
{
  (void)in_sizes; (void)n_in; (void)out_size;
  const float* enc  = (const float*)d_in[0];
  const float* eh   = (const float*)d_in[1];
  const float* ec   = (const float*)d_in[2];
  const int*   tok  = (const int*)d_in[4];
  const float* emb  = (const float*)d_in[5];
  const float* W1   = (const float*)d_in[6];
  const float* b1   = (const float*)d_in[7];
  const float* W2   = (const float*)d_in[8];
  const float* b2   = (const float*)d_in[9];
  const float* Vw   = (const float*)d_in[10];
  const float* Vb   = (const float*)d_in[11];
  const float* W_ih = (const float*)d_in[12];
  const float* W_hh = (const float*)d_in[13];
  const float* b_ih = (const float*)d_in[14];
  const float* b_hh = (const float*)d_in[15];
  const float* outW = (const float*)d_in[16];
  const float* outb = (const float*)d_in[17];
  const float* br1W = (const float*)d_in[18];
  const float* br1b = (const float*)d_in[19];
  const float* br2W = (const float*)d_in[20];
  const float* br2b = (const float*)d_in[21];

  float* out    = (float*)d_out;
  float* out_lp = out;
  float* out_h  = out + (size_t)B * T * V;
  float* out_c  = out_h + B * H;
  float* out_at = out_c + B * H;

  char* wp = (char*)d_ws;
  auto alloc = [&](size_t bytes) {
    char* p = wp; wp += (bytes + 255) & ~(size_t)255; return p;
  };
  float* keys   = (float*)alloc((size_t)S * H * 4);
  float* hbuf0  = (float*)alloc((size_t)B * H * 4);
  float* hbuf1  = (float*)alloc((size_t)B * H * 4);
  float* cbuf0  = (float*)alloc((size_t)B * H * 4);
  float* cbuf1  = (float*)alloc((size_t)B * H * 4);
  float* qW1v   = (float*)alloc((size_t)B * H * 4);
  float* scores = (float*)alloc((size_t)B * S * 4);
  float* xbuf   = (float*)alloc((size_t)B * KX * 4);
  float* gates  = (float*)alloc((size_t)B * H4 * 4);
  float* pmv    = (float*)alloc((size_t)NB_LOGITS * 64 * 4);
  float* plv    = (float*)alloc((size_t)NB_LOGITS * 64 * 4);

  unsigned short* outWb = (unsigned short*)alloc((size_t)V * H * 2);
  size_t need_out = (size_t)(wp - (char*)d_ws);
  unsigned short* wihb = (unsigned short*)alloc((size_t)H4 * 2 * H * 2);
  unsigned short* whhb = (unsigned short*)alloc((size_t)H4 * H * 2);
  unsigned short* w1b  = (unsigned short*)alloc((size_t)H * H * 2);
  size_t need_all = (size_t)(wp - (char*)d_ws);

  const bool cvtOut = ws_size >= need_out;
  const bool cvtAll = ws_size >= need_all;

  if (cvtOut) k_f32_to_bf16<<<4096, 256, 0, stream>>>(outW, outWb, V * H);
  if (cvtAll) {
    k_f32_to_bf16<<<2048, 256, 0, stream>>>(W_ih, wihb, H4 * 2 * H);
    k_f32_to_bf16<<<1024, 256, 0, stream>>>(W_hh, whhb, H4 * H);
    k_f32_to_bf16<<<256, 256, 0, stream>>>(W1, w1b, H * H);
  }

  // prep: keys (S=128 -> two 64-row calls), bridge h0/c0
  gemm64_mfma<<<16, 256, 0, stream>>>(enc,          H, W2, H, W2, H, H, b2, nullptr, keys,          H, H, 0, nullptr, nullptr);
  gemm64_mfma<<<16, 256, 0, stream>>>(enc + 64 * H, H, W2, H, W2, H, H, b2, nullptr, keys + 64 * H, H, H, 0, nullptr, nullptr);
  gemm64_mfma<<<16, 256, 0, stream>>>(eh, H, br1W, H, br1W, H, H, br1b, nullptr, hbuf0, H, H, 0, nullptr, nullptr);
  gemm64_mfma<<<16, 256, 0, stream>>>(ec, H, br2W, H, br2W, H, H, br2b, nullptr, cbuf0, H, H, 0, nullptr, nullptr);

  float* hb[2] = {hbuf0, hbuf1};
  float* cb[2] = {cbuf0, cbuf1};

  for (int t = 0; t < T; ++t) {
    const int cur = t & 1, nxt = cur ^ 1;
    // qW1 = h @ W1^T + b1
    if (cvtAll)
      gemm64_mfma<<<16, 256, 0, stream>>>(hb[cur], H, w1b, H, w1b, H, H, b1, nullptr, qW1v, H, H, 1, nullptr, nullptr);
    else
      gemm64_mfma<<<16, 256, 0, stream>>>(hb[cur], H, W1, H, W1, H, H, b1, nullptr, qW1v, H, H, 0, nullptr, nullptr);
    k_scores<<<256, 256, 0, stream>>>(qW1v, keys, Vw, Vb, scores);
    k_attn_ctx<<<256, 256, 0, stream>>>(scores, enc, emb, tok, hb[cur], xbuf, out_at, t);
    // gates = [emb|ctx] @ W_ih^T + h @ W_hh^T + b_ih + b_hh
    if (cvtAll)
      gemm64_mfma<<<64, 256, 0, stream>>>(xbuf, KX, wihb, 2 * H, whhb, H, 2 * H, b_ih, b_hh, gates, H4, KX, 1, nullptr, nullptr);
    else
      gemm64_mfma<<<64, 256, 0, stream>>>(xbuf, KX, W_ih, 2 * H, W_hh, H, 2 * H, b_ih, b_hh, gates, H4, KX, 0, nullptr, nullptr);
    k_cell<<<256, 256, 0, stream>>>(gates, cb[cur], hb[nxt], cb[nxt], out_h, out_c, t == T - 1);
    // logits = h_new @ outW^T + outb  (written into d_out, plus softmax partials)
    if (cvtOut)
      gemm64_mfma<<<NB_LOGITS, 256, 0, stream>>>(hb[nxt], H, outWb, H, outWb, H, H, outb, nullptr, out_lp + (size_t)t * V, (size_t)T * V, H, 1, pmv, plv);
    else
      gemm64_mfma<<<NB_LOGITS, 256, 0, stream>>>(hb[nxt], H, outW, H, outW, H, H, outb, nullptr, out_lp + (size_t)t * V, (size_t)T * V, H, 0, pmv, plv);
    k_norm<<<64 * 125, 256, 0, stream>>>(pmv, plv, out_lp, t);
  }
}

// Round 2
// 2858.720 us; speedup vs baseline: 2.7551x; 2.7551x over previous
//
#include <hip/hip_runtime.h>
#include <hip/hip_bf16.h>

#define DEV __device__ __forceinline__

constexpr int B = 64, S = 128, T = 32, H = 1024, V = 32000;
constexpr int H4 = 4096;          // 4*H
constexpr int KX = 3072;          // [emb | ctx | h] concat length
constexpr int NBL = V / 64;       // 500 blocks for logits GEMM
constexpr int NQ1 = H / 64;       // 16 blocks for qW1 GEMM

using f32x4   = __attribute__((ext_vector_type(4))) float;
using short8v = __attribute__((ext_vector_type(8))) short;

DEV unsigned short f2bf(float x) {
  union { __hip_bfloat16 b; unsigned short u; } v;
  v.b = __float2bfloat16(x);
  return v.u;
}
DEV float fast_sig(float x) { return 1.0f / (1.0f + __expf(-x)); }
DEV float fast_tanh(float x) {
  float e = __expf(2.0f * x);
  return 1.0f - 2.0f / (e + 1.0f);
}

// async global->LDS, 16B per lane, LDS dest wave-uniform base + lane*16
DEV void gload16(const void* g, void* l) {
  __builtin_amdgcn_global_load_lds(
      (const __attribute__((address_space(1))) void*)g,
      (__attribute__((address_space(3))) void*)l, 16, 0, 0);
}

// f32 -> bf16 bulk convert, n multiple of 8, grid-stride
__global__ __launch_bounds__(256) void k_f32_to_bf16(
    const float* __restrict__ src, unsigned short* __restrict__ dst, int n) {
  int i0 = (blockIdx.x * 256 + threadIdx.x) * 8;
  int stride = gridDim.x * 256 * 8;
  for (int i = i0; i < n; i += stride) {
    float4 a = *(const float4*)(src + i);
    float4 c = *(const float4*)(src + i + 4);
    ushort4 u1, u2;
    u1.x = f2bf(a.x); u1.y = f2bf(a.y); u1.z = f2bf(a.z); u1.w = f2bf(a.w);
    u2.x = f2bf(c.x); u2.y = f2bf(c.y); u2.z = f2bf(c.z); u2.w = f2bf(c.w);
    *(ushort4*)(dst + i)     = u1;
    *(ushort4*)(dst + i + 4) = u2;
  }
}

// ---------------- fast bf16 GEMM (M=64, Ntile=64, BK=64) ----------------
// LDS layout per 64x64 tile (8KB): slab ks(0,1: 32-k) at ks*4096B,
// m-block mb at mb*1024B, lane l holds 16B at l*16 -> frag row=mb*16+(l&15),
// k = ks*32 + (l>>4)*8 .. +7  (identical layout R1 verified).
struct SmemT {
  unsigned short As[2][4096];
  unsigned short Bs[2][4096];
  float Pm[4][64];
  float Pl[4][64];
};

template<bool PARTIALS>
DEV void gemm_body(SmemT& sm,
                   const unsigned short* __restrict__ A, int lda,
                   const unsigned short* __restrict__ W, int ldw,
                   int K, int n0,
                   float* __restrict__ C, size_t ldc,
                   const float* __restrict__ bias,
                   float* __restrict__ pm, float* __restrict__ pl, int pmb)
{
  const int tid = threadIdx.x;
  const int l   = tid & 63;
  const int w   = tid >> 6;

  f32x4 acc0 = {0,0,0,0}, acc1 = {0,0,0,0}, acc2 = {0,0,0,0}, acc3 = {0,0,0,0};

  const int rA = l & 15;            // row within 16-row block
  const int kq = (l >> 4) << 3;     // k offset within 32-slab

  auto stage = [&](int k0, int buf) {
    #pragma unroll
    for (int i = 0; i < 4; ++i) {
      const int c    = (w << 2) | i;      // 0..15
      const int side = c >> 3;            // 0: A, 1: B
      const int ks   = (c >> 2) & 1;
      const int mb   = c & 3;
      const int kk   = k0 + ks * 32 + kq;
      const int row  = mb * 16 + rA;
      const unsigned short* src = side
        ? W + (size_t)(n0 + row) * ldw + kk
        : A + (size_t)row * lda + kk;
      unsigned short* dstBase = side ? &sm.Bs[buf][0] : &sm.As[buf][0];
      gload16(src, dstBase + ks * 2048 + mb * 512);
    }
  };

  const int nk = K >> 6;
  stage(0, 0);
  for (int kt = 0; kt < nk; ++kt) {
    const int buf = kt & 1;
    if (kt + 1 < nk) {
      stage((kt + 1) << 6, buf ^ 1);
      asm volatile("s_waitcnt vmcnt(4)" ::: "memory");
    } else {
      asm volatile("s_waitcnt vmcnt(0)" ::: "memory");
    }
    __syncthreads();
    #pragma unroll
    for (int ks = 0; ks < 2; ++ks) {
      const unsigned short* ab = &sm.As[buf][ks * 2048];
      short8v bf = *(const short8v*)&sm.Bs[buf][ks * 2048 + (w << 9) + (l << 3)];
      acc0 = __builtin_amdgcn_mfma_f32_16x16x32_bf16(*(const short8v*)&ab[0 * 512 + (l << 3)], bf, acc0, 0, 0, 0);
      acc1 = __builtin_amdgcn_mfma_f32_16x16x32_bf16(*(const short8v*)&ab[1 * 512 + (l << 3)], bf, acc1, 0, 0, 0);
      acc2 = __builtin_amdgcn_mfma_f32_16x16x32_bf16(*(const short8v*)&ab[2 * 512 + (l << 3)], bf, acc2, 0, 0, 0);
      acc3 = __builtin_amdgcn_mfma_f32_16x16x32_bf16(*(const short8v*)&ab[3 * 512 + (l << 3)], bf, acc3, 0, 0, 0);
    }
    __syncthreads();
  }

  const int col = n0 + (w << 4) + (l & 15);
  const float bv = bias ? bias[col] : 0.0f;
  f32x4 accs[4] = {acc0, acc1, acc2, acc3};
  float vals[4][4];
  #pragma unroll
  for (int mb = 0; mb < 4; ++mb) {
    #pragma unroll
    for (int r = 0; r < 4; ++r) {
      int row = (mb << 4) + ((l >> 4) << 2) + r;
      float v = accs[mb][r] + bv;
      vals[mb][r] = v;
      C[(size_t)row * ldc + col] = v;
    }
  }

  if (PARTIALS) {
    #pragma unroll
    for (int mb = 0; mb < 4; ++mb) {
      #pragma unroll
      for (int r = 0; r < 4; ++r) {
        float v = vals[mb][r];
        float m = v;
        #pragma unroll
        for (int d = 1; d < 16; d <<= 1) m = fmaxf(m, __shfl_xor(m, d));
        float e = __expf(v - m);
        #pragma unroll
        for (int d = 1; d < 16; d <<= 1) e += __shfl_xor(e, d);
        if ((l & 15) == 0) {
          int row = (mb << 4) + ((l >> 4) << 2) + r;
          sm.Pm[w][row] = m;
          sm.Pl[w][row] = e;
        }
      }
    }
    __syncthreads();
    if (tid < 64) {
      float M = sm.Pm[0][tid];
      M = fmaxf(M, sm.Pm[1][tid]); M = fmaxf(M, sm.Pm[2][tid]); M = fmaxf(M, sm.Pm[3][tid]);
      float L = sm.Pl[0][tid] * __expf(sm.Pm[0][tid] - M)
              + sm.Pl[1][tid] * __expf(sm.Pm[1][tid] - M)
              + sm.Pl[2][tid] * __expf(sm.Pm[2][tid] - M)
              + sm.Pl[3][tid] * __expf(sm.Pm[3][tid] - M);
      pm[(size_t)pmb * 64 + tid] = M;
      pl[(size_t)pmb * 64 + tid] = L;
    }
  }
}

// combined logits(t-1) + qW1(t) GEMM; both read A = hbf (h_t bf16, 64xH)
__global__ __launch_bounds__(256) void k_gemm_combined(
    const unsigned short* __restrict__ hbf,
    const unsigned short* __restrict__ outWb, float* __restrict__ lp_t,
    const float* __restrict__ outb, float* __restrict__ pm, float* __restrict__ pl,
    int nb0,
    const unsigned short* __restrict__ w1b, float* __restrict__ qW1v,
    const float* __restrict__ b1)
{
  __shared__ SmemT sm;
  const int bx = blockIdx.x;
  if (bx < nb0)
    gemm_body<true>(sm, hbf, H, outWb, H, H, bx * 64, lp_t, (size_t)T * V, outb, pm, pl, bx);
  else
    gemm_body<false>(sm, hbf, H, w1b, H, H, (bx - nb0) * 64, qW1v, H, b1, nullptr, nullptr, 0);
}

// gates GEMM split-K x3: grid 192, kc = bx>>6, writes gpart[kc][B][4H]
__global__ __launch_bounds__(256) void k_gates(
    const unsigned short* __restrict__ xbufb,
    const unsigned short* __restrict__ wihb,
    const unsigned short* __restrict__ whhb,
    float* __restrict__ gpart)
{
  __shared__ SmemT sm;
  const int bx = blockIdx.x;
  const int kc = bx >> 6, nb = bx & 63;
  const unsigned short* A = xbufb + kc * 1024;
  const unsigned short* W = (kc == 2) ? whhb : wihb + kc * 1024;
  const int ldw = (kc == 2) ? H : 2 * H;
  gemm_body<false>(sm, A, KX, W, ldw, H, nb * 64,
                   gpart + (size_t)kc * B * H4, (size_t)H4, nullptr, nullptr, nullptr, 0);
}

// generic single GEMM (prep keys/bridges use legacy f32 kernel below instead)

// scores + logZ(t-1): bx<nsc -> scores (b=bx>>2, 32 s each); else logZ for b=bx-nsc
__global__ __launch_bounds__(256) void k_scores_logz(
    const float* __restrict__ qW1, const float* __restrict__ keys,
    const float* __restrict__ Vw, const float* __restrict__ Vb,
    float* __restrict__ scores,
    const float* __restrict__ pm, const float* __restrict__ pl,
    float* __restrict__ logZ, int nsc)
{
  const int bx = blockIdx.x;
  const int tid = threadIdx.x;
  if (bx < nsc) {
    __shared__ float qw[H];
    __shared__ float vw[H];
    const int b  = bx >> 2;
    const int sq = bx & 3;
    #pragma unroll
    for (int i = 0; i < 4; ++i) {
      qw[tid + i * 256] = qW1[b * H + tid + i * 256];
      vw[tid + i * 256] = Vw[tid + i * 256];
    }
    __syncthreads();
    const int w = tid >> 6, lane = tid & 63;
    #pragma unroll
    for (int si = 0; si < 8; ++si) {
      int sg = sq * 32 + w * 8 + si;
      const float* kp = keys + (size_t)sg * H;
      float p = 0.0f;
      #pragma unroll
      for (int u = 0; u < 16; ++u) {
        int h = lane + (u << 6);
        p += vw[h] * fast_tanh(qw[h] + kp[h]);
      }
      #pragma unroll
      for (int d = 1; d < 64; d <<= 1) p += __shfl_xor(p, d);
      if (lane == 0) scores[b * S + sg] = p + Vb[0];
    }
  } else {
    __shared__ float rm[256], rl[256];
    const int b = bx - nsc;
    float m1 = pm[(size_t)tid * 64 + b];
    float l1 = pl[(size_t)tid * 64 + b];
    int j2 = tid + 256;
    if (j2 < NBL) {
      float m2 = pm[(size_t)j2 * 64 + b], l2 = pl[(size_t)j2 * 64 + b];
      float M = fmaxf(m1, m2);
      l1 = l1 * __expf(m1 - M) + l2 * __expf(m2 - M);
      m1 = M;
    }
    rm[tid] = m1; rl[tid] = l1;
    __syncthreads();
    for (int off = 128; off > 0; off >>= 1) {
      if (tid < off) {
        float ma = rm[tid], mb2 = rm[tid + off];
        float M = fmaxf(ma, mb2);
        rl[tid] = rl[tid] * __expf(ma - M) + rl[tid + off] * __expf(mb2 - M);
        rm[tid] = M;
      }
      __syncthreads();
    }
    if (tid == 0) logZ[b] = rm[0] + __logf(rl[0]);
  }
}

// attn softmax+context+xbuf(bf16)  |  normalize(t-1): lp -= logZ[b]
__global__ __launch_bounds__(256) void k_attn_norm(
    const float* __restrict__ scores, const float* __restrict__ enc,
    const float* __restrict__ emb, const int* __restrict__ tok,
    const unsigned short* __restrict__ hbf, unsigned short* __restrict__ xbufb,
    float* __restrict__ attn_out, int t,
    float* __restrict__ lpn, const float* __restrict__ logZ, int natt)
{
  const int bx = blockIdx.x;
  const int tid = threadIdx.x;
  if (bx < natt) {
    __shared__ float al[S];
    __shared__ float wred[4];
    const int b  = bx >> 2;
    const int hq = bx & 3;

    float sv = (tid < S) ? scores[b * S + tid] : -1e30f;
    float m = sv;
    #pragma unroll
    for (int d = 1; d < 64; d <<= 1) m = fmaxf(m, __shfl_xor(m, d));
    if ((tid & 63) == 0) wred[tid >> 6] = m;
    __syncthreads();
    m = fmaxf(fmaxf(wred[0], wred[1]), fmaxf(wred[2], wred[3]));
    float e = (tid < S) ? __expf(sv - m) : 0.0f;
    float ssum = e;
    #pragma unroll
    for (int d = 1; d < 64; d <<= 1) ssum += __shfl_xor(ssum, d);
    __syncthreads();
    if ((tid & 63) == 0) wred[tid >> 6] = ssum;
    __syncthreads();
    float tot = wred[0] + wred[1] + wred[2] + wred[3];
    float a = e / tot;
    if (tid < S) {
      al[tid] = a;
      if (hq == 0) attn_out[((size_t)t * B + b) * S + tid] = a;
    }
    __syncthreads();

    const int h = hq * 256 + tid;
    float acc = 0.0f;
    const float* ep = enc + (size_t)b * S * H + h;
    #pragma unroll 4
    for (int s = 0; s < S; ++s) acc += al[s] * ep[(size_t)s * H];

    int token = tok[b * T + t];
    xbufb[(size_t)b * KX + h]         = f2bf(emb[(size_t)token * H + h]);
    xbufb[(size_t)b * KX + H + h]     = f2bf(acc);
    xbufb[(size_t)b * KX + 2 * H + h] = hbf[b * H + h];
  } else {
    const int j = bx - natt;                   // 0..1999
    size_t e0 = (size_t)j * 1024 + tid * 4;
    int b = (int)(e0 / V);
    int r = (int)(e0 - (size_t)b * V);
    float4* p = (float4*)(lpn + (size_t)b * T * V + r);
    float z = logZ[b];
    float4 v = *p;
    v.x -= z; v.y -= z; v.z -= z; v.w -= z;
    *p = v;
  }
}

// LSTM cell: sum 3 gate partials + biases, write c (f32) and h (bf16)
__global__ __launch_bounds__(256) void k_cell3(
    const float* __restrict__ gpart, const float* __restrict__ b_ih,
    const float* __restrict__ b_hh, const float* __restrict__ cprev,
    float* __restrict__ cnew, unsigned short* __restrict__ hbf,
    float* __restrict__ out_h, float* __restrict__ out_c, int last)
{
  const int idx = blockIdx.x * 256 + threadIdx.x;
  const int b = idx >> 10, h = idx & 1023;
  const float* g0 = gpart + (size_t)b * H4;
  const float* g1 = g0 + (size_t)B * H4;
  const float* g2 = g1 + (size_t)B * H4;
  float gi = g0[h]         + g1[h]         + g2[h]         + b_ih[h]         + b_hh[h];
  float gf = g0[H + h]     + g1[H + h]     + g2[H + h]     + b_ih[H + h]     + b_hh[H + h];
  float gg = g0[2 * H + h] + g1[2 * H + h] + g2[2 * H + h] + b_ih[2 * H + h] + b_hh[2 * H + h];
  float go = g0[3 * H + h] + g1[3 * H + h] + g2[3 * H + h] + b_ih[3 * H + h] + b_hh[3 * H + h];
  float c = fast_sig(gf) * cprev[idx] + fast_sig(gi) * fast_tanh(gg);
  float hv = fast_sig(go) * fast_tanh(c);
  cnew[idx] = c;
  hbf[idx] = f2bf(hv);
  if (last) { out_h[idx] = hv; out_c[idx] = c; }
}

// ================= legacy (R1) kernels: prep GEMMs + ws fallback ==========
__global__ __launch_bounds__(256) void gemm64_mfma(
    const float* __restrict__ A, int lda,
    const void* __restrict__ Wa, int ldwa,
    const void* __restrict__ Wb, int ldwb, int ksplit,
    const float* __restrict__ bias1, const float* __restrict__ bias2,
    float* __restrict__ C, size_t ldc,
    int K, int wbf16,
    float* __restrict__ pm, float* __restrict__ pl)
{
  __shared__ unsigned short As[2048];
  __shared__ unsigned short Bs[2048];
  __shared__ float Pm[4][64];
  __shared__ float Pl[4][64];

  const int tid  = threadIdx.x;
  const int lane = tid & 63;
  const int w    = tid >> 6;
  const int n0   = blockIdx.x * 64;

  f32x4 acc0 = {0.f,0.f,0.f,0.f}, acc1 = {0.f,0.f,0.f,0.f};
  f32x4 acc2 = {0.f,0.f,0.f,0.f}, acc3 = {0.f,0.f,0.f,0.f};

  for (int k0 = 0; k0 < K; k0 += 32) {
    #pragma unroll
    for (int ss = 0; ss < 2; ++ss) {
      int s  = tid + ss * 256;
      int r  = s >> 3;
      int kq = s & 7;
      int kL = kq * 4;
      int kg = k0 + kL;
      const float* ap = A + (size_t)r * lda + kg;
      float4 av = *(const float4*)ap;
      ushort4 au;
      au.x = f2bf(av.x); au.y = f2bf(av.y); au.z = f2bf(av.z); au.w = f2bf(av.w);
      int dst = ((r >> 4) << 9) + ((kL >> 3) << 7) + ((r & 15) << 3) + (kL & 7);
      *(ushort4*)&As[dst] = au;
      int n = n0 + r;
      ushort4 bu;
      if (wbf16) {
        const unsigned short* wpp = (kg < ksplit)
          ? (const unsigned short*)Wa + (size_t)n * ldwa + kg
          : (const unsigned short*)Wb + (size_t)n * ldwb + (kg - ksplit);
        bu = *(const ushort4*)wpp;
      } else {
        const float* wpp = (kg < ksplit)
          ? (const float*)Wa + (size_t)n * ldwa + kg
          : (const float*)Wb + (size_t)n * ldwb + (kg - ksplit);
        float4 wv = *(const float4*)wpp;
        bu.x = f2bf(wv.x); bu.y = f2bf(wv.y); bu.z = f2bf(wv.z); bu.w = f2bf(wv.w);
      }
      *(ushort4*)&Bs[dst] = bu;
    }
    __syncthreads();
    short8v bf = *(const short8v*)&Bs[(w << 9) + (lane << 3)];
    short8v a0 = *(const short8v*)&As[(0 << 9) + (lane << 3)];
    short8v a1 = *(const short8v*)&As[(1 << 9) + (lane << 3)];
    short8v a2 = *(const short8v*)&As[(2 << 9) + (lane << 3)];
    short8v a3 = *(const short8v*)&As[(3 << 9) + (lane << 3)];
    acc0 = __builtin_amdgcn_mfma_f32_16x16x32_bf16(a0, bf, acc0, 0, 0, 0);
    acc1 = __builtin_amdgcn_mfma_f32_16x16x32_bf16(a1, bf, acc1, 0, 0, 0);
    acc2 = __builtin_amdgcn_mfma_f32_16x16x32_bf16(a2, bf, acc2, 0, 0, 0);
    acc3 = __builtin_amdgcn_mfma_f32_16x16x32_bf16(a3, bf, acc3, 0, 0, 0);
    __syncthreads();
  }

  const int col = n0 + (w << 4) + (lane & 15);
  const float bv = (bias1 ? bias1[col] : 0.0f) + (bias2 ? bias2[col] : 0.0f);
  f32x4 accs[4] = {acc0, acc1, acc2, acc3};
  float vals[4][4];
  #pragma unroll
  for (int mb = 0; mb < 4; ++mb) {
    #pragma unroll
    for (int r = 0; r < 4; ++r) {
      int row = (mb << 4) + ((lane >> 4) << 2) + r;
      float v = accs[mb][r] + bv;
      vals[mb][r] = v;
      C[(size_t)row * ldc + col] = v;
    }
  }

  if (pm) {
    #pragma unroll
    for (int mb = 0; mb < 4; ++mb) {
      #pragma unroll
      for (int r = 0; r < 4; ++r) {
        float v = vals[mb][r];
        float m = v;
        #pragma unroll
        for (int d = 1; d < 16; d <<= 1) m = fmaxf(m, __shfl_xor(m, d));
        float e = __expf(v - m);
        #pragma unroll
        for (int d = 1; d < 16; d <<= 1) e += __shfl_xor(e, d);
        if ((lane & 15) == 0) {
          int row = (mb << 4) + ((lane >> 4) << 2) + r;
          Pm[w][row] = m;
          Pl[w][row] = e;
        }
      }
    }
    __syncthreads();
    if (tid < 64) {
      float M = Pm[0][tid];
      M = fmaxf(M, Pm[1][tid]); M = fmaxf(M, Pm[2][tid]); M = fmaxf(M, Pm[3][tid]);
      float L = Pl[0][tid] * __expf(Pm[0][tid] - M)
              + Pl[1][tid] * __expf(Pm[1][tid] - M)
              + Pl[2][tid] * __expf(Pm[2][tid] - M)
              + Pl[3][tid] * __expf(Pm[3][tid] - M);
      pm[(size_t)blockIdx.x * 64 + tid] = M;
      pl[(size_t)blockIdx.x * 64 + tid] = L;
    }
  }
}

__global__ __launch_bounds__(256) void k_attn_ctx_leg(
    const float* __restrict__ scores, const float* __restrict__ enc,
    const float* __restrict__ emb, const int* __restrict__ tok,
    const float* __restrict__ hcur, float* __restrict__ xbuf,
    float* __restrict__ attn_out, int t)
{
  __shared__ float al[S];
  __shared__ float wred[4];
  const int b   = blockIdx.x >> 2;
  const int hq  = blockIdx.x & 3;
  const int tid = threadIdx.x;

  float sv = (tid < S) ? scores[b * S + tid] : -1e30f;
  float m = sv;
  #pragma unroll
  for (int d = 1; d < 64; d <<= 1) m = fmaxf(m, __shfl_xor(m, d));
  if ((tid & 63) == 0) wred[tid >> 6] = m;
  __syncthreads();
  m = fmaxf(fmaxf(wred[0], wred[1]), fmaxf(wred[2], wred[3]));
  float e = (tid < S) ? __expf(sv - m) : 0.0f;
  float ssum = e;
  #pragma unroll
  for (int d = 1; d < 64; d <<= 1) ssum += __shfl_xor(ssum, d);
  __syncthreads();
  if ((tid & 63) == 0) wred[tid >> 6] = ssum;
  __syncthreads();
  float tot = wred[0] + wred[1] + wred[2] + wred[3];
  float a = e / tot;
  if (tid < S) {
    al[tid] = a;
    if (hq == 0) attn_out[((size_t)t * B + b) * S + tid] = a;
  }
  __syncthreads();

  const int h = hq * 256 + tid;
  float acc = 0.0f;
  const float* ep = enc + (size_t)b * S * H + h;
  #pragma unroll 4
  for (int s = 0; s < S; ++s) acc += al[s] * ep[(size_t)s * H];

  int token = tok[b * T + t];
  xbuf[b * KX + h]         = emb[(size_t)token * H + h];
  xbuf[b * KX + H + h]     = acc;
  xbuf[b * KX + 2 * H + h] = hcur[b * H + h];
}

__global__ __launch_bounds__(256) void k_cell_leg(
    const float* __restrict__ gates, const float* __restrict__ cprev,
    float* __restrict__ hnew, float* __restrict__ cnew,
    float* __restrict__ hout, float* __restrict__ cout, int last)
{
  int idx = blockIdx.x * 256 + threadIdx.x;
  int b = idx >> 10, h = idx & 1023;
  const float* g = gates + (size_t)b * H4;
  float gi = g[h], gf = g[H + h], gg = g[2 * H + h], go = g[3 * H + h];
  float c = fast_sig(gf) * cprev[idx] + fast_sig(gi) * fast_tanh(gg);
  float hv = fast_sig(go) * fast_tanh(c);
  cnew[idx] = c;
  hnew[idx] = hv;
  if (last) { hout[idx] = hv; cout[idx] = c; }
}

__global__ __launch_bounds__(256) void k_norm_leg(
    const float* __restrict__ pm, const float* __restrict__ pl,
    float* __restrict__ lp, int t)
{
  __shared__ float rm[256], rl[256];
  const int bx = blockIdx.x;
  const int b  = bx / 125;
  const int ch = bx % 125;
  const int tid = threadIdx.x;

  float m1 = pm[(size_t)tid * 64 + b];
  float l1 = pl[(size_t)tid * 64 + b];
  int nb2 = tid + 256;
  if (nb2 < NBL) {
    float m2 = pm[(size_t)nb2 * 64 + b];
    float l2 = pl[(size_t)nb2 * 64 + b];
    float M = fmaxf(m1, m2);
    l1 = l1 * __expf(m1 - M) + l2 * __expf(m2 - M);
    m1 = M;
  }
  rm[tid] = m1; rl[tid] = l1;
  __syncthreads();
  for (int off = 128; off > 0; off >>= 1) {
    if (tid < off) {
      float ma = rm[tid], mb = rm[tid + off];
      float M = fmaxf(ma, mb);
      rl[tid] = rl[tid] * __expf(ma - M) + rl[tid + off] * __expf(mb - M);
      rm[tid] = M;
    }
    __syncthreads();
  }
  float logZ = rm[0] + __logf(rl[0]);
  size_t base = ((size_t)b * T + t) * V + (size_t)ch * 256;
  lp[base + tid] -= logZ;
}

// ============================ host launcher ================================
extern "C" void kernel_launch(void* const* d_in, const int* in_sizes, int n_in,
                              void* d_out, int out_size, void* d_ws, size_t ws_size,
                              hipStream_t stream)
{
  (void)in_sizes; (void)n_in; (void)out_size;
  const float* enc  = (const float*)d_in[0];
  const float* eh   = (const float*)d_in[1];
  const float* ec   = (const float*)d_in[2];
  const int*   tok  = (const int*)d_in[4];
  const float* emb  = (const float*)d_in[5];
  const float* W1   = (const float*)d_in[6];
  const float* b1   = (const float*)d_in[7];
  const float* W2   = (const float*)d_in[8];
  const float* b2   = (const float*)d_in[9];
  const float* Vw   = (const float*)d_in[10];
  const float* Vb   = (const float*)d_in[11];
  const float* W_ih = (const float*)d_in[12];
  const float* W_hh = (const float*)d_in[13];
  const float* b_ih = (const float*)d_in[14];
  const float* b_hh = (const float*)d_in[15];
  const float* outW = (const float*)d_in[16];
  const float* outb = (const float*)d_in[17];
  const float* br1W = (const float*)d_in[18];
  const float* br1b = (const float*)d_in[19];
  const float* br2W = (const float*)d_in[20];
  const float* br2b = (const float*)d_in[21];

  float* out    = (float*)d_out;
  float* out_lp = out;
  float* out_h  = out + (size_t)B * T * V;
  float* out_c  = out_h + B * H;
  float* out_at = out_c + B * H;

  // ---------------- fast-path workspace layout ----------------
  char* wp = (char*)d_ws;
  auto alloc = [&](size_t bytes) {
    char* p = wp; wp += (bytes + 255) & ~(size_t)255; return p;
  };
  float* keys   = (float*)alloc((size_t)S * H * 4);
  float* cbuf0  = (float*)alloc((size_t)B * H * 4);
  float* cbuf1  = (float*)alloc((size_t)B * H * 4);
  float* qW1v   = (float*)alloc((size_t)B * H * 4);
  float* scores = (float*)alloc((size_t)B * S * 4);
  unsigned short* xbufb = (unsigned short*)alloc((size_t)B * KX * 2);
  float* gpart  = (float*)alloc((size_t)3 * B * H4 * 4);
  float* pmv    = (float*)alloc((size_t)NBL * 64 * 4);
  float* plv    = (float*)alloc((size_t)NBL * 64 * 4);
  float* logZ   = (float*)alloc((size_t)B * 4);
  unsigned short* hbf = (unsigned short*)alloc((size_t)B * H * 2);
  unsigned short* outWb = (unsigned short*)alloc((size_t)V * H * 2);
  unsigned short* wihb  = (unsigned short*)alloc((size_t)H4 * 2 * H * 2);
  unsigned short* whhb  = (unsigned short*)alloc((size_t)H4 * H * 2);
  unsigned short* w1b   = (unsigned short*)alloc((size_t)H * H * 2);
  size_t need_fast = (size_t)(wp - (char*)d_ws);

  if (ws_size >= need_fast) {
    // ---------------- fast path ----------------
    k_f32_to_bf16<<<4096, 256, 0, stream>>>(outW, outWb, V * H);
    k_f32_to_bf16<<<2048, 256, 0, stream>>>(W_ih, wihb, H4 * 2 * H);
    k_f32_to_bf16<<<1024, 256, 0, stream>>>(W_hh, whhb, H4 * H);
    k_f32_to_bf16<<<256, 256, 0, stream>>>(W1, w1b, H * H);

    // prep GEMMs (legacy f32-staging kernel; runs once)
    gemm64_mfma<<<16, 256, 0, stream>>>(enc,          H, W2, H, W2, H, H, b2, nullptr, keys,          H, H, 0, nullptr, nullptr);
    gemm64_mfma<<<16, 256, 0, stream>>>(enc + 64 * H, H, W2, H, W2, H, H, b2, nullptr, keys + 64 * H, H, H, 0, nullptr, nullptr);
    gemm64_mfma<<<16, 256, 0, stream>>>(eh, H, br1W, H, br1W, H, H, br1b, nullptr, gpart, H, H, 0, nullptr, nullptr); // h0 -> gpart temp
    gemm64_mfma<<<16, 256, 0, stream>>>(ec, H, br2W, H, br2W, H, H, br2b, nullptr, cbuf0, H, H, 0, nullptr, nullptr);
    k_f32_to_bf16<<<32, 256, 0, stream>>>(gpart, hbf, B * H);  // h0 bf16

    float* cb[2] = {cbuf0, cbuf1};

    for (int t = 0; t < T; ++t) {
      const int nb0 = (t > 0) ? NBL : 0;
      k_gemm_combined<<<nb0 + NQ1, 256, 0, stream>>>(
          hbf, outWb, out_lp + (size_t)(t - 1) * V, outb, pmv, plv, nb0,
          w1b, qW1v, b1);
      k_scores_logz<<<256 + (t > 0 ? 64 : 0), 256, 0, stream>>>(
          qW1v, keys, Vw, Vb, scores, pmv, plv, logZ, 256);
      k_attn_norm<<<256 + (t > 0 ? 2000 : 0), 256, 0, stream>>>(
          scores, enc, emb, tok, hbf, xbufb, out_at, t,
          out_lp + (size_t)(t - 1) * V, logZ, 256);
      k_gates<<<192, 256, 0, stream>>>(xbufb, wihb, whhb, gpart);
      k_cell3<<<256, 256, 0, stream>>>(gpart, b_ih, b_hh, cb[t & 1],
                                       cb[(t & 1) ^ 1], hbf, out_h, out_c, t == T - 1);
    }
    // finale: logits(T-1), logZ, normalize
    k_gemm_combined<<<NBL, 256, 0, stream>>>(
        hbf, outWb, out_lp + (size_t)(T - 1) * V, outb, pmv, plv, NBL,
        w1b, qW1v, b1);
    k_scores_logz<<<64, 256, 0, stream>>>(
        qW1v, keys, Vw, Vb, scores, pmv, plv, logZ, 0);
    k_attn_norm<<<2000, 256, 0, stream>>>(
        scores, enc, emb, tok, hbf, xbufb, out_at, 0,
        out_lp + (size_t)(T - 1) * V, logZ, 0);
    return;
  }

  // ---------------- legacy fallback (R1 flow) ----------------
  wp = (char*)d_ws;
  float* keysL   = (float*)alloc((size_t)S * H * 4);
  float* hbuf0   = (float*)alloc((size_t)B * H * 4);
  float* hbuf1   = (float*)alloc((size_t)B * H * 4);
  float* cbuf0L  = (float*)alloc((size_t)B * H * 4);
  float* cbuf1L  = (float*)alloc((size_t)B * H * 4);
  float* qW1vL   = (float*)alloc((size_t)B * H * 4);
  float* scoresL = (float*)alloc((size_t)B * S * 4);
  float* xbuf    = (float*)alloc((size_t)B * KX * 4);
  float* gates   = (float*)alloc((size_t)B * H4 * 4);
  float* pmvL    = (float*)alloc((size_t)NBL * 64 * 4);
  float* plvL    = (float*)alloc((size_t)NBL * 64 * 4);
  unsigned short* outWbL = (unsigned short*)alloc((size_t)V * H * 2);
  size_t need_out = (size_t)(wp - (char*)d_ws);
  unsigned short* wihbL = (unsigned short*)alloc((size_t)H4 * 2 * H * 2);
  unsigned short* whhbL = (unsigned short*)alloc((size_t)H4 * H * 2);
  unsigned short* w1bL  = (unsigned short*)alloc((size_t)H * H * 2);
  size_t need_all = (size_t)(wp - (char*)d_ws);

  const bool cvtOut = ws_size >= need_out;
  const bool cvtAll = ws_size >= need_all;

  if (cvtOut) k_f32_to_bf16<<<4096, 256, 0, stream>>>(outW, outWbL, V * H);
  if (cvtAll) {
    k_f32_to_bf16<<<2048, 256, 0, stream>>>(W_ih, wihbL, H4 * 2 * H);
    k_f32_to_bf16<<<1024, 256, 0, stream>>>(W_hh, whhbL, H4 * H);
    k_f32_to_bf16<<<256, 256, 0, stream>>>(W1, w1bL, H * H);
  }

  gemm64_mfma<<<16, 256, 0, stream>>>(enc,          H, W2, H, W2, H, H, b2, nullptr, keysL,          H, H, 0, nullptr, nullptr);
  gemm64_mfma<<<16, 256, 0, stream>>>(enc + 64 * H, H, W2, H, W2, H, H, b2, nullptr, keysL + 64 * H, H, H, 0, nullptr, nullptr);
  gemm64_mfma<<<16, 256, 0, stream>>>(eh, H, br1W, H, br1W, H, H, br1b, nullptr, hbuf0, H, H, 0, nullptr, nullptr);
  gemm64_mfma<<<16, 256, 0, stream>>>(ec, H, br2W, H, br2W, H, H, br2b, nullptr, cbuf0L, H, H, 0, nullptr, nullptr);

  float* hb[2] = {hbuf0, hbuf1};
  float* cb[2] = {cbuf0L, cbuf1L};

  for (int t = 0; t < T; ++t) {
    const int cur = t & 1, nxt = cur ^ 1;
    if (cvtAll)
      gemm64_mfma<<<16, 256, 0, stream>>>(hb[cur], H, w1bL, H, w1bL, H, H, b1, nullptr, qW1vL, H, H, 1, nullptr, nullptr);
    else
      gemm64_mfma<<<16, 256, 0, stream>>>(hb[cur], H, W1, H, W1, H, H, b1, nullptr, qW1vL, H, H, 0, nullptr, nullptr);
    k_scores_logz<<<256, 256, 0, stream>>>(qW1vL, keysL, Vw, Vb, scoresL, pmvL, plvL, nullptr, 256);
    k_attn_ctx_leg<<<256, 256, 0, stream>>>(scoresL, enc, emb, tok, hb[cur], xbuf, out_at, t);
    if (cvtAll)
      gemm64_mfma<<<64, 256, 0, stream>>>(xbuf, KX, wihbL, 2 * H, whhbL, H, 2 * H, b_ih, b_hh, gates, H4, KX, 1, nullptr, nullptr);
    else
      gemm64_mfma<<<64, 256, 0, stream>>>(xbuf, KX, W_ih, 2 * H, W_hh, H, 2 * H, b_ih, b_hh, gates, H4, KX, 0, nullptr, nullptr);
    k_cell_leg<<<256, 256, 0, stream>>>(gates, cb[cur], hb[nxt], cb[nxt], out_h, out_c, t == T - 1);
    if (cvtOut)
      gemm64_mfma<<<NBL, 256, 0, stream>>>(hb[nxt], H, outWbL, H, outWbL, H, H, outb, nullptr, out_lp + (size_t)t * V, (size_t)T * V, H, 1, pmvL, plvL);
    else
      gemm64_mfma<<<NBL, 256, 0, stream>>>(hb[nxt], H, outW, H, outW, H, H, outb, nullptr, out_lp + (size_t)t * V, (size_t)T * V, H, 0, pmvL, plvL);
    k_norm_leg<<<64 * 125, 256, 0, stream>>>(pmvL, plvL, out_lp, t);
  }
}

// Round 3
// 2699.663 us; speedup vs baseline: 2.9174x; 1.0589x over previous
//
#include <hip/hip_runtime.h>
#include <hip/hip_bf16.h>

#define DEV __device__ __forceinline__

constexpr int B = 64, S = 128, T = 32, H = 1024, V = 32000;
constexpr int H4 = 4096;          // 4*H
constexpr int KX = 3072;          // [emb | ctx | h] concat length
constexpr int NBL = V / 64;       // 500 tiles for logits GEMM

using f32x4   = __attribute__((ext_vector_type(4))) float;
using short8v = __attribute__((ext_vector_type(8))) short;

DEV unsigned short f2bf(float x) {
  union { __hip_bfloat16 b; unsigned short u; } v;
  v.b = __float2bfloat16(x);
  return v.u;
}
DEV float fast_sig(float x) { return 1.0f / (1.0f + __expf(-x)); }
DEV float fast_tanh(float x) {
  float e = __expf(2.0f * x);
  return 1.0f - 2.0f / (e + 1.0f);
}

// async global->LDS, 16B per lane; LDS dest = wave-uniform base + lane*16
DEV void gload16(const void* g, void* l) {
  __builtin_amdgcn_global_load_lds(
      (const __attribute__((address_space(1))) void*)g,
      (__attribute__((address_space(3))) void*)l, 16, 0, 0);
}

// f32 -> bf16 bulk convert, n multiple of 8, grid-stride
__global__ __launch_bounds__(256) void k_f32_to_bf16(
    const float* __restrict__ src, unsigned short* __restrict__ dst, int n) {
  int i0 = (blockIdx.x * 256 + threadIdx.x) * 8;
  int stride = gridDim.x * 256 * 8;
  for (int i = i0; i < n; i += stride) {
    float4 a = *(const float4*)(src + i);
    float4 c = *(const float4*)(src + i + 4);
    ushort4 u1, u2;
    u1.x = f2bf(a.x); u1.y = f2bf(a.y); u1.z = f2bf(a.z); u1.w = f2bf(a.w);
    u2.x = f2bf(c.x); u2.y = f2bf(c.y); u2.z = f2bf(c.z); u2.w = f2bf(c.w);
    *(ushort4*)(dst + i)     = u1;
    *(ushort4*)(dst + i + 4) = u2;
  }
}

// ============ pipelined bf16 GEMM body (M=64, Ntile=64, BK=64) ============
// 3 LDS buffers, 2-deep prefetch, raw s_barrier + counted vmcnt.
// LDS layout per 64x64 tile: slab ks at ks*2048 shorts, m-block mb at mb*512,
// lane l's 16B at l*16 -> frag row=mb*16+(l&15), k=ks*32+(l>>4)*8..+7.
struct GemmSm {
  unsigned short As[3][4096];
  unsigned short Bs[3][4096];
  float Pm[4][64];
  float Pl[4][64];
};
struct ScoresSm { float qw[H]; float vw[H]; };
struct AttnSm   { float al[S]; float wred[4]; };
union StepSm { GemmSm g; ScoresSm s; AttnSm a; };

template<bool PARTIALS>
DEV void gemm_body2(GemmSm& sm,
                    const unsigned short* __restrict__ A, int lda,
                    const unsigned short* __restrict__ W, int ldw,
                    int K, int n0,
                    float* __restrict__ C, size_t ldc,
                    const float* __restrict__ bias,
                    float* __restrict__ pm, float* __restrict__ pl, int pmb)
{
  const int tid = threadIdx.x;
  const int l   = tid & 63;
  const int w   = tid >> 6;

  f32x4 acc0 = {0,0,0,0}, acc1 = {0,0,0,0}, acc2 = {0,0,0,0}, acc3 = {0,0,0,0};

  const int rA = l & 15;            // row within 16-row block
  const int kq = (l >> 4) << 3;     // k offset within 32-slab

  auto stage = [&](int k0, int buf) {
    #pragma unroll
    for (int i = 0; i < 4; ++i) {
      const int c    = (w << 2) | i;      // 0..15
      const int side = c >> 3;            // 0: A, 1: B
      const int ks   = (c >> 2) & 1;
      const int mb   = c & 3;
      const int kk   = k0 + ks * 32 + kq;
      const int row  = mb * 16 + rA;
      const unsigned short* src = side
        ? W + (size_t)(n0 + row) * ldw + kk
        : A + (size_t)row * lda + kk;
      unsigned short* dst = (side ? sm.Bs[buf] : sm.As[buf]) + ks * 2048 + mb * 512;
      gload16(src, dst);
    }
  };

  const int nk = K >> 6;
  stage(0, 0);
  if (nk > 1) stage(64, 1);
  for (int kt = 0; kt < nk; ++kt) {
    const int buf = kt % 3;
    if (kt + 2 < nk) {
      stage((kt + 2) << 6, (kt + 2) % 3);
      asm volatile("s_waitcnt vmcnt(8)" ::: "memory");
    } else if (kt + 1 < nk) {
      asm volatile("s_waitcnt vmcnt(4)" ::: "memory");
    } else {
      asm volatile("s_waitcnt vmcnt(0)" ::: "memory");
    }
    __builtin_amdgcn_s_barrier();
    asm volatile("" ::: "memory");
    const unsigned short* __restrict__ asb = sm.As[buf];
    const unsigned short* __restrict__ bsb = sm.Bs[buf];
    #pragma unroll
    for (int ks = 0; ks < 2; ++ks) {
      short8v bf = *(const short8v*)&bsb[ks * 2048 + (w << 9) + (l << 3)];
      acc0 = __builtin_amdgcn_mfma_f32_16x16x32_bf16(*(const short8v*)&asb[ks * 2048 + 0 * 512 + (l << 3)], bf, acc0, 0, 0, 0);
      acc1 = __builtin_amdgcn_mfma_f32_16x16x32_bf16(*(const short8v*)&asb[ks * 2048 + 1 * 512 + (l << 3)], bf, acc1, 0, 0, 0);
      acc2 = __builtin_amdgcn_mfma_f32_16x16x32_bf16(*(const short8v*)&asb[ks * 2048 + 2 * 512 + (l << 3)], bf, acc2, 0, 0, 0);
      acc3 = __builtin_amdgcn_mfma_f32_16x16x32_bf16(*(const short8v*)&asb[ks * 2048 + 3 * 512 + (l << 3)], bf, acc3, 0, 0, 0);
    }
    asm volatile("" ::: "memory");
    __builtin_amdgcn_s_barrier();
  }

  // epilogue: C/D frag mapping col = lane&15, row = (lane>>4)*4 + r (+16*mb)
  const int col = n0 + (w << 4) + (l & 15);
  const float bv = bias ? bias[col] : 0.0f;
  f32x4 accs[4] = {acc0, acc1, acc2, acc3};
  float vals[4][4];
  #pragma unroll
  for (int mb = 0; mb < 4; ++mb) {
    #pragma unroll
    for (int r = 0; r < 4; ++r) {
      int row = (mb << 4) + ((l >> 4) << 2) + r;
      float v = accs[mb][r] + bv;
      vals[mb][r] = v;
      C[(size_t)row * ldc + col] = v;
    }
  }

  if (PARTIALS) {
    #pragma unroll
    for (int mb = 0; mb < 4; ++mb) {
      #pragma unroll
      for (int r = 0; r < 4; ++r) {
        float v = vals[mb][r];
        float m = v;
        #pragma unroll
        for (int d = 1; d < 16; d <<= 1) m = fmaxf(m, __shfl_xor(m, d));
        float e = __expf(v - m);
        #pragma unroll
        for (int d = 1; d < 16; d <<= 1) e += __shfl_xor(e, d);
        if ((l & 15) == 0) {
          int row = (mb << 4) + ((l >> 4) << 2) + r;
          sm.Pm[w][row] = m;
          sm.Pl[w][row] = e;
        }
      }
    }
    __syncthreads();
    if (tid < 64) {
      float M = sm.Pm[0][tid];
      M = fmaxf(M, sm.Pm[1][tid]); M = fmaxf(M, sm.Pm[2][tid]); M = fmaxf(M, sm.Pm[3][tid]);
      float L = sm.Pl[0][tid] * __expf(sm.Pm[0][tid] - M)
              + sm.Pl[1][tid] * __expf(sm.Pm[1][tid] - M)
              + sm.Pl[2][tid] * __expf(sm.Pm[2][tid] - M)
              + sm.Pl[3][tid] * __expf(sm.Pm[3][tid] - M);
      pm[(size_t)pmb * 64 + tid] = M;
      pl[(size_t)pmb * 64 + tid] = L;
    }
  }
}

// normalize 4096 elems of lp(t') : lp[b, t', r] -= logZ[b]
DEV void norm_apply(int j, float* __restrict__ lp_base, const float* __restrict__ logZ, int tid) {
  #pragma unroll
  for (int q = 0; q < 4; ++q) {
    size_t e = (size_t)j * 4096 + q * 1024 + tid * 4;
    int b = (int)(e / 32000);
    int r = (int)(e - (size_t)b * 32000);
    float4* p = (float4*)(lp_base + (size_t)b * T * V + r);
    float z = logZ[b];
    float4 v = *p;
    v.x -= z; v.y -= z; v.z -= z; v.w -= z;
    *p = v;
  }
}

// ---------------- step kernel 1: qW1 split-K x4 + logits chunk A + norm(t-2)
__global__ __launch_bounds__(256) void k_step1(
    const unsigned short* __restrict__ hbf, const unsigned short* __restrict__ w1b,
    float* __restrict__ qW1p,
    const unsigned short* __restrict__ outWb, float* __restrict__ lp_prev,
    const float* __restrict__ outb, float* __restrict__ pm, float* __restrict__ pl,
    int chn, int nrm, float* __restrict__ lp_norm, const float* __restrict__ logZ)
{
  __shared__ StepSm sm;
  const int bx = blockIdx.x;
  if (bx < 64) {
    const int kc = bx >> 4, nb = bx & 15;
    gemm_body2<false>(sm.g, hbf + kc * 256, H, w1b + kc * 256, H, 256, nb * 64,
                      qW1p + (size_t)kc * B * H, H, nullptr, nullptr, nullptr, 0);
  } else if (bx < 64 + chn) {
    const int tile = bx - 64;   // 0..124
    gemm_body2<true>(sm.g, hbf, H, outWb, H, H, tile * 64,
                     lp_prev, (size_t)T * V, outb, pm, pl, tile);
  } else {
    norm_apply(bx - 64 - chn, lp_norm, logZ, threadIdx.x);
  }
}

// ---------------- step kernel 2: scores (256 blocks) + logits chunk B
__global__ __launch_bounds__(256) void k_step2(
    const float* __restrict__ qW1p, const float* __restrict__ b1,
    const float* __restrict__ keys, const float* __restrict__ Vw,
    const float* __restrict__ Vb, float* __restrict__ scores,
    const unsigned short* __restrict__ hbf,
    const unsigned short* __restrict__ outWb, float* __restrict__ lp_prev,
    const float* __restrict__ outb, float* __restrict__ pm, float* __restrict__ pl)
{
  __shared__ StepSm sm;
  const int bx = blockIdx.x;
  const int tid = threadIdx.x;
  if (bx < 256) {
    const int b  = bx >> 2;
    const int sq = bx & 3;
    #pragma unroll
    for (int i = 0; i < 4; ++i) {
      int idx = tid + i * 256;
      float q = b1[idx];
      q += qW1p[(size_t)0 * B * H + b * H + idx];
      q += qW1p[(size_t)1 * B * H + b * H + idx];
      q += qW1p[(size_t)2 * B * H + b * H + idx];
      q += qW1p[(size_t)3 * B * H + b * H + idx];
      sm.s.qw[idx] = q;
      sm.s.vw[idx] = Vw[idx];
    }
    __syncthreads();
    const int w = tid >> 6, lane = tid & 63;
    #pragma unroll
    for (int si = 0; si < 8; ++si) {
      int sg = sq * 32 + w * 8 + si;
      const float* kp = keys + (size_t)sg * H;
      float p = 0.0f;
      #pragma unroll
      for (int u = 0; u < 16; ++u) {
        int h = lane + (u << 6);
        p += sm.s.vw[h] * fast_tanh(sm.s.qw[h] + kp[h]);
      }
      #pragma unroll
      for (int d = 1; d < 64; d <<= 1) p += __shfl_xor(p, d);
      if (lane == 0) scores[b * S + sg] = p + Vb[0];
    }
  } else {
    const int tile = 125 + (bx - 256);
    gemm_body2<true>(sm.g, hbf, H, outWb, H, H, tile * 64,
                     lp_prev, (size_t)T * V, outb, pm, pl, tile);
  }
}

// ---------------- step kernel 3: attn softmax+ctx+xbuf + logits chunk C
__global__ __launch_bounds__(256) void k_step3(
    const float* __restrict__ scores, const float* __restrict__ enc,
    const float* __restrict__ emb, const int* __restrict__ tok,
    const unsigned short* __restrict__ hbf, unsigned short* __restrict__ xbufb,
    float* __restrict__ attn_out, int t,
    const unsigned short* __restrict__ outWb, float* __restrict__ lp_prev,
    const float* __restrict__ outb, float* __restrict__ pm, float* __restrict__ pl)
{
  __shared__ StepSm sm;
  const int bx = blockIdx.x;
  const int tid = threadIdx.x;
  if (bx < 256) {
    const int b  = bx >> 2;
    const int hq = bx & 3;
    float sv = (tid < S) ? scores[b * S + tid] : -1e30f;
    float m = sv;
    #pragma unroll
    for (int d = 1; d < 64; d <<= 1) m = fmaxf(m, __shfl_xor(m, d));
    if ((tid & 63) == 0) sm.a.wred[tid >> 6] = m;
    __syncthreads();
    m = fmaxf(fmaxf(sm.a.wred[0], sm.a.wred[1]), fmaxf(sm.a.wred[2], sm.a.wred[3]));
    float e = (tid < S) ? __expf(sv - m) : 0.0f;
    float ssum = e;
    #pragma unroll
    for (int d = 1; d < 64; d <<= 1) ssum += __shfl_xor(ssum, d);
    __syncthreads();
    if ((tid & 63) == 0) sm.a.wred[tid >> 6] = ssum;
    __syncthreads();
    float tot = sm.a.wred[0] + sm.a.wred[1] + sm.a.wred[2] + sm.a.wred[3];
    float a = e / tot;
    if (tid < S) {
      sm.a.al[tid] = a;
      if (hq == 0) attn_out[((size_t)t * B + b) * S + tid] = a;
    }
    __syncthreads();

    const int h = hq * 256 + tid;
    float acc = 0.0f;
    const float* ep = enc + (size_t)b * S * H + h;
    #pragma unroll 4
    for (int s = 0; s < S; ++s) acc += sm.a.al[s] * ep[(size_t)s * H];

    int token = tok[b * T + t];
    xbufb[(size_t)b * KX + h]         = f2bf(emb[(size_t)token * H + h]);
    xbufb[(size_t)b * KX + H + h]     = f2bf(acc);
    xbufb[(size_t)b * KX + 2 * H + h] = hbf[b * H + h];
  } else {
    const int tile = 250 + (bx - 256);
    gemm_body2<true>(sm.g, hbf, H, outWb, H, H, tile * 64,
                     lp_prev, (size_t)T * V, outb, pm, pl, tile);
  }
}

// ---------------- step kernel 4: gates split-K x6 (384) + logits chunk D
__global__ __launch_bounds__(256) void k_step4(
    const unsigned short* __restrict__ xbufb,
    const unsigned short* __restrict__ wihb,
    const unsigned short* __restrict__ whhb,
    float* __restrict__ gpart,
    const unsigned short* __restrict__ hbf,
    const unsigned short* __restrict__ outWb, float* __restrict__ lp_prev,
    const float* __restrict__ outb, float* __restrict__ pm, float* __restrict__ pl)
{
  __shared__ StepSm sm;
  const int bx = blockIdx.x;
  if (bx < 384) {
    const int kc = bx >> 6, nb = bx & 63;
    const unsigned short* A;
    const unsigned short* W;
    int ldw;
    if (kc < 4) { A = xbufb + kc * 512; W = wihb + kc * 512; ldw = 2 * H; }
    else        { A = xbufb + 2048 + (kc - 4) * 512; W = whhb + (kc - 4) * 512; ldw = H; }
    gemm_body2<false>(sm.g, A, KX, W, ldw, 512, nb * 64,
                      gpart + (size_t)kc * B * H4, (size_t)H4, nullptr, nullptr, nullptr, 0);
  } else {
    const int tile = 375 + (bx - 384);
    gemm_body2<true>(sm.g, hbf, H, outWb, H, H, tile * 64,
                     lp_prev, (size_t)T * V, outb, pm, pl, tile);
  }
}

// ---------------- step kernel 5: cell (6 partials) + logZ(t-1)
__global__ __launch_bounds__(256) void k_step5(
    const float* __restrict__ gpart, const float* __restrict__ b_ih,
    const float* __restrict__ b_hh, const float* __restrict__ cprev,
    float* __restrict__ cnew, unsigned short* __restrict__ hbf,
    float* __restrict__ out_h, float* __restrict__ out_c, int last,
    const float* __restrict__ pm, const float* __restrict__ pl,
    float* __restrict__ logZ)
{
  __shared__ float rm[256], rl[256];
  const int bx = blockIdx.x;
  const int tid = threadIdx.x;
  if (bx < 256) {
    const int idx = bx * 256 + tid;
    const int b = idx >> 10, h = idx & 1023;
    float gi = b_ih[h]         + b_hh[h];
    float gf = b_ih[H + h]     + b_hh[H + h];
    float gg = b_ih[2 * H + h] + b_hh[2 * H + h];
    float go = b_ih[3 * H + h] + b_hh[3 * H + h];
    #pragma unroll
    for (int p = 0; p < 6; ++p) {
      const float* g = gpart + (size_t)p * B * H4 + (size_t)b * H4;
      gi += g[h]; gf += g[H + h]; gg += g[2 * H + h]; go += g[3 * H + h];
    }
    float c = fast_sig(gf) * cprev[idx] + fast_sig(gi) * fast_tanh(gg);
    float hv = fast_sig(go) * fast_tanh(c);
    cnew[idx] = c;
    hbf[idx] = f2bf(hv);
    if (last) { out_h[idx] = hv; out_c[idx] = c; }
  } else {
    const int b = bx - 256;
    float m1 = pm[(size_t)tid * 64 + b];
    float l1 = pl[(size_t)tid * 64 + b];
    int j2 = tid + 256;
    if (j2 < NBL) {
      float m2 = pm[(size_t)j2 * 64 + b], l2 = pl[(size_t)j2 * 64 + b];
      float M = fmaxf(m1, m2);
      l1 = l1 * __expf(m1 - M) + l2 * __expf(m2 - M);
      m1 = M;
    }
    rm[tid] = m1; rl[tid] = l1;
    __syncthreads();
    for (int off = 128; off > 0; off >>= 1) {
      if (tid < off) {
        float ma = rm[tid], mb2 = rm[tid + off];
        float M = fmaxf(ma, mb2);
        rl[tid] = rl[tid] * __expf(ma - M) + rl[tid + off] * __expf(mb2 - M);
        rm[tid] = M;
      }
      __syncthreads();
    }
    if (tid == 0) logZ[b] = rm[0] + __logf(rl[0]);
  }
}

// ---------------- finale: logits(T-1) full + norm(T-2); then logZ; then norm
__global__ __launch_bounds__(256) void k_fin1(
    const unsigned short* __restrict__ hbf,
    const unsigned short* __restrict__ outWb, float* __restrict__ lp_last,
    const float* __restrict__ outb, float* __restrict__ pm, float* __restrict__ pl,
    float* __restrict__ lp_norm, const float* __restrict__ logZ)
{
  __shared__ StepSm sm;
  const int bx = blockIdx.x;
  if (bx < NBL) {
    gemm_body2<true>(sm.g, hbf, H, outWb, H, H, bx * 64,
                     lp_last, (size_t)T * V, outb, pm, pl, bx);
  } else {
    norm_apply(bx - NBL, lp_norm, logZ, threadIdx.x);
  }
}

__global__ __launch_bounds__(256) void k_logz_fin(
    const float* __restrict__ pm, const float* __restrict__ pl,
    float* __restrict__ logZ)
{
  __shared__ float rm[256], rl[256];
  const int b = blockIdx.x;
  const int tid = threadIdx.x;
  float m1 = pm[(size_t)tid * 64 + b];
  float l1 = pl[(size_t)tid * 64 + b];
  int j2 = tid + 256;
  if (j2 < NBL) {
    float m2 = pm[(size_t)j2 * 64 + b], l2 = pl[(size_t)j2 * 64 + b];
    float M = fmaxf(m1, m2);
    l1 = l1 * __expf(m1 - M) + l2 * __expf(m2 - M);
    m1 = M;
  }
  rm[tid] = m1; rl[tid] = l1;
  __syncthreads();
  for (int off = 128; off > 0; off >>= 1) {
    if (tid < off) {
      float ma = rm[tid], mb2 = rm[tid + off];
      float M = fmaxf(ma, mb2);
      rl[tid] = rl[tid] * __expf(ma - M) + rl[tid + off] * __expf(mb2 - M);
      rm[tid] = M;
    }
    __syncthreads();
  }
  if (tid == 0) logZ[b] = rm[0] + __logf(rl[0]);
}

__global__ __launch_bounds__(256) void k_norm_fin(
    float* __restrict__ lp_base, const float* __restrict__ logZ)
{
  norm_apply(blockIdx.x, lp_base, logZ, threadIdx.x);
}

// ================= legacy (R1/R2) kernels: prep GEMMs + ws fallback ========
__global__ __launch_bounds__(256) void gemm64_mfma(
    const float* __restrict__ A, int lda,
    const void* __restrict__ Wa, int ldwa,
    const void* __restrict__ Wb, int ldwb, int ksplit,
    const float* __restrict__ bias1, const float* __restrict__ bias2,
    float* __restrict__ C, size_t ldc,
    int K, int wbf16,
    float* __restrict__ pm, float* __restrict__ pl)
{
  __shared__ unsigned short As[2048];
  __shared__ unsigned short Bs[2048];
  __shared__ float Pm[4][64];
  __shared__ float Pl[4][64];

  const int tid  = threadIdx.x;
  const int lane = tid & 63;
  const int w    = tid >> 6;
  const int n0   = blockIdx.x * 64;

  f32x4 acc0 = {0.f,0.f,0.f,0.f}, acc1 = {0.f,0.f,0.f,0.f};
  f32x4 acc2 = {0.f,0.f,0.f,0.f}, acc3 = {0.f,0.f,0.f,0.f};

  for (int k0 = 0; k0 < K; k0 += 32) {
    #pragma unroll
    for (int ss = 0; ss < 2; ++ss) {
      int s  = tid + ss * 256;
      int r  = s >> 3;
      int kq = s & 7;
      int kL = kq * 4;
      int kg = k0 + kL;
      const float* ap = A + (size_t)r * lda + kg;
      float4 av = *(const float4*)ap;
      ushort4 au;
      au.x = f2bf(av.x); au.y = f2bf(av.y); au.z = f2bf(av.z); au.w = f2bf(av.w);
      int dst = ((r >> 4) << 9) + ((kL >> 3) << 7) + ((r & 15) << 3) + (kL & 7);
      *(ushort4*)&As[dst] = au;
      int n = n0 + r;
      ushort4 bu;
      if (wbf16) {
        const unsigned short* wpp = (kg < ksplit)
          ? (const unsigned short*)Wa + (size_t)n * ldwa + kg
          : (const unsigned short*)Wb + (size_t)n * ldwb + (kg - ksplit);
        bu = *(const ushort4*)wpp;
      } else {
        const float* wpp = (kg < ksplit)
          ? (const float*)Wa + (size_t)n * ldwa + kg
          : (const float*)Wb + (size_t)n * ldwb + (kg - ksplit);
        float4 wv = *(const float4*)wpp;
        bu.x = f2bf(wv.x); bu.y = f2bf(wv.y); bu.z = f2bf(wv.z); bu.w = f2bf(wv.w);
      }
      *(ushort4*)&Bs[dst] = bu;
    }
    __syncthreads();
    short8v bf = *(const short8v*)&Bs[(w << 9) + (lane << 3)];
    short8v a0 = *(const short8v*)&As[(0 << 9) + (lane << 3)];
    short8v a1 = *(const short8v*)&As[(1 << 9) + (lane << 3)];
    short8v a2 = *(const short8v*)&As[(2 << 9) + (lane << 3)];
    short8v a3 = *(const short8v*)&As[(3 << 9) + (lane << 3)];
    acc0 = __builtin_amdgcn_mfma_f32_16x16x32_bf16(a0, bf, acc0, 0, 0, 0);
    acc1 = __builtin_amdgcn_mfma_f32_16x16x32_bf16(a1, bf, acc1, 0, 0, 0);
    acc2 = __builtin_amdgcn_mfma_f32_16x16x32_bf16(a2, bf, acc2, 0, 0, 0);
    acc3 = __builtin_amdgcn_mfma_f32_16x16x32_bf16(a3, bf, acc3, 0, 0, 0);
    __syncthreads();
  }

  const int col = n0 + (w << 4) + (lane & 15);
  const float bv = (bias1 ? bias1[col] : 0.0f) + (bias2 ? bias2[col] : 0.0f);
  f32x4 accs[4] = {acc0, acc1, acc2, acc3};
  float vals[4][4];
  #pragma unroll
  for (int mb = 0; mb < 4; ++mb) {
    #pragma unroll
    for (int r = 0; r < 4; ++r) {
      int row = (mb << 4) + ((lane >> 4) << 2) + r;
      float v = accs[mb][r] + bv;
      vals[mb][r] = v;
      C[(size_t)row * ldc + col] = v;
    }
  }

  if (pm) {
    #pragma unroll
    for (int mb = 0; mb < 4; ++mb) {
      #pragma unroll
      for (int r = 0; r < 4; ++r) {
        float v = vals[mb][r];
        float m = v;
        #pragma unroll
        for (int d = 1; d < 16; d <<= 1) m = fmaxf(m, __shfl_xor(m, d));
        float e = __expf(v - m);
        #pragma unroll
        for (int d = 1; d < 16; d <<= 1) e += __shfl_xor(e, d);
        if ((lane & 15) == 0) {
          int row = (mb << 4) + ((lane >> 4) << 2) + r;
          Pm[w][row] = m;
          Pl[w][row] = e;
        }
      }
    }
    __syncthreads();
    if (tid < 64) {
      float M = Pm[0][tid];
      M = fmaxf(M, Pm[1][tid]); M = fmaxf(M, Pm[2][tid]); M = fmaxf(M, Pm[3][tid]);
      float L = Pl[0][tid] * __expf(Pm[0][tid] - M)
              + Pl[1][tid] * __expf(Pm[1][tid] - M)
              + Pl[2][tid] * __expf(Pm[2][tid] - M)
              + Pl[3][tid] * __expf(Pm[3][tid] - M);
      pm[(size_t)blockIdx.x * 64 + tid] = M;
      pl[(size_t)blockIdx.x * 64 + tid] = L;
    }
  }
}

__global__ __launch_bounds__(256) void k_scores_leg(
    const float* __restrict__ qW1, const float* __restrict__ keys,
    const float* __restrict__ Vw, const float* __restrict__ Vb,
    float* __restrict__ scores)
{
  __shared__ float qw[H];
  __shared__ float vw[H];
  const int b  = blockIdx.x >> 2;
  const int sq = blockIdx.x & 3;
  const int tid = threadIdx.x;
  #pragma unroll
  for (int i = 0; i < 4; ++i) {
    qw[tid + i * 256] = qW1[b * H + tid + i * 256];
    vw[tid + i * 256] = Vw[tid + i * 256];
  }
  __syncthreads();
  const int w = tid >> 6, lane = tid & 63;
  #pragma unroll
  for (int si = 0; si < 8; ++si) {
    int sg = sq * 32 + w * 8 + si;
    const float* kp = keys + (size_t)sg * H;
    float p = 0.0f;
    #pragma unroll
    for (int u = 0; u < 16; ++u) {
      int h = lane + (u << 6);
      p += vw[h] * fast_tanh(qw[h] + kp[h]);
    }
    #pragma unroll
    for (int d = 1; d < 64; d <<= 1) p += __shfl_xor(p, d);
    if (lane == 0) scores[b * S + sg] = p + Vb[0];
  }
}

__global__ __launch_bounds__(256) void k_attn_ctx_leg(
    const float* __restrict__ scores, const float* __restrict__ enc,
    const float* __restrict__ emb, const int* __restrict__ tok,
    const float* __restrict__ hcur, float* __restrict__ xbuf,
    float* __restrict__ attn_out, int t)
{
  __shared__ float al[S];
  __shared__ float wred[4];
  const int b   = blockIdx.x >> 2;
  const int hq  = blockIdx.x & 3;
  const int tid = threadIdx.x;

  float sv = (tid < S) ? scores[b * S + tid] : -1e30f;
  float m = sv;
  #pragma unroll
  for (int d = 1; d < 64; d <<= 1) m = fmaxf(m, __shfl_xor(m, d));
  if ((tid & 63) == 0) wred[tid >> 6] = m;
  __syncthreads();
  m = fmaxf(fmaxf(wred[0], wred[1]), fmaxf(wred[2], wred[3]));
  float e = (tid < S) ? __expf(sv - m) : 0.0f;
  float ssum = e;
  #pragma unroll
  for (int d = 1; d < 64; d <<= 1) ssum += __shfl_xor(ssum, d);
  __syncthreads();
  if ((tid & 63) == 0) wred[tid >> 6] = ssum;
  __syncthreads();
  float tot = wred[0] + wred[1] + wred[2] + wred[3];
  float a = e / tot;
  if (tid < S) {
    al[tid] = a;
    if (hq == 0) attn_out[((size_t)t * B + b) * S + tid] = a;
  }
  __syncthreads();

  const int h = hq * 256 + tid;
  float acc = 0.0f;
  const float* ep = enc + (size_t)b * S * H + h;
  #pragma unroll 4
  for (int s = 0; s < S; ++s) acc += al[s] * ep[(size_t)s * H];

  int token = tok[b * T + t];
  xbuf[b * KX + h]         = emb[(size_t)token * H + h];
  xbuf[b * KX + H + h]     = acc;
  xbuf[b * KX + 2 * H + h] = hcur[b * H + h];
}

__global__ __launch_bounds__(256) void k_cell_leg(
    const float* __restrict__ gates, const float* __restrict__ cprev,
    float* __restrict__ hnew, float* __restrict__ cnew,
    float* __restrict__ hout, float* __restrict__ cout, int last)
{
  int idx = blockIdx.x * 256 + threadIdx.x;
  int b = idx >> 10, h = idx & 1023;
  const float* g = gates + (size_t)b * H4;
  float gi = g[h], gf = g[H + h], gg = g[2 * H + h], go = g[3 * H + h];
  float c = fast_sig(gf) * cprev[idx] + fast_sig(gi) * fast_tanh(gg);
  float hv = fast_sig(go) * fast_tanh(c);
  cnew[idx] = c;
  hnew[idx] = hv;
  if (last) { hout[idx] = hv; cout[idx] = c; }
}

__global__ __launch_bounds__(256) void k_norm_leg(
    const float* __restrict__ pm, const float* __restrict__ pl,
    float* __restrict__ lp, int t)
{
  __shared__ float rm[256], rl[256];
  const int bx = blockIdx.x;
  const int b  = bx / 125;
  const int ch = bx % 125;
  const int tid = threadIdx.x;

  float m1 = pm[(size_t)tid * 64 + b];
  float l1 = pl[(size_t)tid * 64 + b];
  int nb2 = tid + 256;
  if (nb2 < NBL) {
    float m2 = pm[(size_t)nb2 * 64 + b];
    float l2 = pl[(size_t)nb2 * 64 + b];
    float M = fmaxf(m1, m2);
    l1 = l1 * __expf(m1 - M) + l2 * __expf(m2 - M);
    m1 = M;
  }
  rm[tid] = m1; rl[tid] = l1;
  __syncthreads();
  for (int off = 128; off > 0; off >>= 1) {
    if (tid < off) {
      float ma = rm[tid], mb = rm[tid + off];
      float M = fmaxf(ma, mb);
      rl[tid] = rl[tid] * __expf(ma - M) + rl[tid + off] * __expf(mb - M);
      rm[tid] = M;
    }
    __syncthreads();
  }
  float logZ = rm[0] + __logf(rl[0]);
  size_t base = ((size_t)b * T + t) * V + (size_t)ch * 256;
  lp[base + tid] -= logZ;
}

// ============================ host launcher ================================
extern "C" void kernel_launch(void* const* d_in, const int* in_sizes, int n_in,
                              void* d_out, int out_size, void* d_ws, size_t ws_size,
                              hipStream_t stream)
{
  (void)in_sizes; (void)n_in; (void)out_size;
  const float* enc  = (const float*)d_in[0];
  const float* eh   = (const float*)d_in[1];
  const float* ec   = (const float*)d_in[2];
  const int*   tok  = (const int*)d_in[4];
  const float* emb  = (const float*)d_in[5];
  const float* W1   = (const float*)d_in[6];
  const float* b1   = (const float*)d_in[7];
  const float* W2   = (const float*)d_in[8];
  const float* b2   = (const float*)d_in[9];
  const float* Vw   = (const float*)d_in[10];
  const float* Vb   = (const float*)d_in[11];
  const float* W_ih = (const float*)d_in[12];
  const float* W_hh = (const float*)d_in[13];
  const float* b_ih = (const float*)d_in[14];
  const float* b_hh = (const float*)d_in[15];
  const float* outW = (const float*)d_in[16];
  const float* outb = (const float*)d_in[17];
  const float* br1W = (const float*)d_in[18];
  const float* br1b = (const float*)d_in[19];
  const float* br2W = (const float*)d_in[20];
  const float* br2b = (const float*)d_in[21];

  float* out    = (float*)d_out;
  float* out_lp = out;
  float* out_h  = out + (size_t)B * T * V;
  float* out_c  = out_h + B * H;
  float* out_at = out_c + B * H;

  // ---------------- fast-path workspace layout ----------------
  char* wp = (char*)d_ws;
  auto alloc = [&](size_t bytes) {
    char* p = wp; wp += (bytes + 255) & ~(size_t)255; return p;
  };
  float* keys   = (float*)alloc((size_t)S * H * 4);
  float* cbuf0  = (float*)alloc((size_t)B * H * 4);
  float* cbuf1  = (float*)alloc((size_t)B * H * 4);
  float* qW1p   = (float*)alloc((size_t)4 * B * H * 4);
  float* scores = (float*)alloc((size_t)B * S * 4);
  unsigned short* xbufb = (unsigned short*)alloc((size_t)B * KX * 2);
  float* gpart  = (float*)alloc((size_t)6 * B * H4 * 4);
  float* pmv    = (float*)alloc((size_t)NBL * 64 * 4);
  float* plv    = (float*)alloc((size_t)NBL * 64 * 4);
  float* logZ   = (float*)alloc((size_t)B * 4);
  unsigned short* hbf = (unsigned short*)alloc((size_t)B * H * 2);
  unsigned short* outWb = (unsigned short*)alloc((size_t)V * H * 2);
  unsigned short* wihb  = (unsigned short*)alloc((size_t)H4 * 2 * H * 2);
  unsigned short* whhb  = (unsigned short*)alloc((size_t)H4 * H * 2);
  unsigned short* w1b   = (unsigned short*)alloc((size_t)H * H * 2);
  size_t need_fast = (size_t)(wp - (char*)d_ws);

  if (ws_size >= need_fast) {
    // weight conversions
    k_f32_to_bf16<<<4096, 256, 0, stream>>>(outW, outWb, V * H);
    k_f32_to_bf16<<<2048, 256, 0, stream>>>(W_ih, wihb, H4 * 2 * H);
    k_f32_to_bf16<<<1024, 256, 0, stream>>>(W_hh, whhb, H4 * H);
    k_f32_to_bf16<<<256, 256, 0, stream>>>(W1, w1b, H * H);

    // prep GEMMs (legacy f32-staging kernel; runs once)
    gemm64_mfma<<<16, 256, 0, stream>>>(enc,          H, W2, H, W2, H, H, b2, nullptr, keys,          H, H, 0, nullptr, nullptr);
    gemm64_mfma<<<16, 256, 0, stream>>>(enc + 64 * H, H, W2, H, W2, H, H, b2, nullptr, keys + 64 * H, H, H, 0, nullptr, nullptr);
    gemm64_mfma<<<16, 256, 0, stream>>>(eh, H, br1W, H, br1W, H, H, br1b, nullptr, gpart, H, H, 0, nullptr, nullptr); // h0 temp
    gemm64_mfma<<<16, 256, 0, stream>>>(ec, H, br2W, H, br2W, H, H, br2b, nullptr, cbuf0, H, H, 0, nullptr, nullptr);
    k_f32_to_bf16<<<32, 256, 0, stream>>>(gpart, hbf, B * H);  // h0 -> bf16

    float* cb[2] = {cbuf0, cbuf1};

    for (int t = 0; t < T; ++t) {
      const int chn = (t >= 1) ? 125 : 0;
      const int nrm = (t >= 2) ? 500 : 0;
      float* lp_prev = out_lp + (size_t)(t - 1) * V;   // valid when chn>0
      float* lp_norm = out_lp + (size_t)(t - 2) * V;   // valid when nrm>0
      k_step1<<<64 + chn + nrm, 256, 0, stream>>>(
          hbf, w1b, qW1p, outWb, lp_prev, outb, pmv, plv, chn, nrm, lp_norm, logZ);
      k_step2<<<256 + chn, 256, 0, stream>>>(
          qW1p, b1, keys, Vw, Vb, scores, hbf, outWb, lp_prev, outb, pmv, plv);
      k_step3<<<256 + chn, 256, 0, stream>>>(
          scores, enc, emb, tok, hbf, xbufb, out_at, t, outWb, lp_prev, outb, pmv, plv);
      k_step4<<<384 + chn, 256, 0, stream>>>(
          xbufb, wihb, whhb, gpart, hbf, outWb, lp_prev, outb, pmv, plv);
      k_step5<<<256 + (t >= 1 ? 64 : 0), 256, 0, stream>>>(
          gpart, b_ih, b_hh, cb[t & 1], cb[(t & 1) ^ 1], hbf, out_h, out_c,
          t == T - 1, pmv, plv, logZ);
    }
    // finale: logits(T-1) + norm(T-2); logZ(T-1); norm(T-1)
    k_fin1<<<NBL + 500, 256, 0, stream>>>(
        hbf, outWb, out_lp + (size_t)(T - 1) * V, outb, pmv, plv,
        out_lp + (size_t)(T - 2) * V, logZ);
    k_logz_fin<<<64, 256, 0, stream>>>(pmv, plv, logZ);
    k_norm_fin<<<500, 256, 0, stream>>>(out_lp + (size_t)(T - 1) * V, logZ);
    return;
  }

  // ---------------- legacy fallback (R1 flow) ----------------
  wp = (char*)d_ws;
  float* keysL   = (float*)alloc((size_t)S * H * 4);
  float* hbuf0   = (float*)alloc((size_t)B * H * 4);
  float* hbuf1   = (float*)alloc((size_t)B * H * 4);
  float* cbuf0L  = (float*)alloc((size_t)B * H * 4);
  float* cbuf1L  = (float*)alloc((size_t)B * H * 4);
  float* qW1vL   = (float*)alloc((size_t)B * H * 4);
  float* scoresL = (float*)alloc((size_t)B * S * 4);
  float* xbuf    = (float*)alloc((size_t)B * KX * 4);
  float* gates   = (float*)alloc((size_t)B * H4 * 4);
  float* pmvL    = (float*)alloc((size_t)NBL * 64 * 4);
  float* plvL    = (float*)alloc((size_t)NBL * 64 * 4);
  unsigned short* outWbL = (unsigned short*)alloc((size_t)V * H * 2);
  size_t need_out = (size_t)(wp - (char*)d_ws);
  unsigned short* wihbL = (unsigned short*)alloc((size_t)H4 * 2 * H * 2);
  unsigned short* whhbL = (unsigned short*)alloc((size_t)H4 * H * 2);
  unsigned short* w1bL  = (unsigned short*)alloc((size_t)H * H * 2);
  size_t need_all = (size_t)(wp - (char*)d_ws);

  const bool cvtOut = ws_size >= need_out;
  const bool cvtAll = ws_size >= need_all;

  if (cvtOut) k_f32_to_bf16<<<4096, 256, 0, stream>>>(outW, outWbL, V * H);
  if (cvtAll) {
    k_f32_to_bf16<<<2048, 256, 0, stream>>>(W_ih, wihbL, H4 * 2 * H);
    k_f32_to_bf16<<<1024, 256, 0, stream>>>(W_hh, whhbL, H4 * H);
    k_f32_to_bf16<<<256, 256, 0, stream>>>(W1, w1bL, H * H);
  }

  gemm64_mfma<<<16, 256, 0, stream>>>(enc,          H, W2, H, W2, H, H, b2, nullptr, keysL,          H, H, 0, nullptr, nullptr);
  gemm64_mfma<<<16, 256, 0, stream>>>(enc + 64 * H, H, W2, H, W2, H, H, b2, nullptr, keysL + 64 * H, H, H, 0, nullptr, nullptr);
  gemm64_mfma<<<16, 256, 0, stream>>>(eh, H, br1W, H, br1W, H, H, br1b, nullptr, hbuf0, H, H, 0, nullptr, nullptr);
  gemm64_mfma<<<16, 256, 0, stream>>>(ec, H, br2W, H, br2W, H, H, br2b, nullptr, cbuf0L, H, H, 0, nullptr, nullptr);

  float* hb[2] = {hbuf0, hbuf1};
  float* cb[2] = {cbuf0L, cbuf1L};

  for (int t = 0; t < T; ++t) {
    const int cur = t & 1, nxt = cur ^ 1;
    if (cvtAll)
      gemm64_mfma<<<16, 256, 0, stream>>>(hb[cur], H, w1bL, H, w1bL, H, H, b1, nullptr, qW1vL, H, H, 1, nullptr, nullptr);
    else
      gemm64_mfma<<<16, 256, 0, stream>>>(hb[cur], H, W1, H, W1, H, H, b1, nullptr, qW1vL, H, H, 0, nullptr, nullptr);
    k_scores_leg<<<256, 256, 0, stream>>>(qW1vL, keysL, Vw, Vb, scoresL);
    k_attn_ctx_leg<<<256, 256, 0, stream>>>(scoresL, enc, emb, tok, hb[cur], xbuf, out_at, t);
    if (cvtAll)
      gemm64_mfma<<<64, 256, 0, stream>>>(xbuf, KX, wihbL, 2 * H, whhbL, H, 2 * H, b_ih, b_hh, gates, H4, KX, 1, nullptr, nullptr);
    else
      gemm64_mfma<<<64, 256, 0, stream>>>(xbuf, KX, W_ih, 2 * H, W_hh, H, 2 * H, b_ih, b_hh, gates, H4, KX, 0, nullptr, nullptr);
    k_cell_leg<<<256, 256, 0, stream>>>(gates, cb[cur], hb[nxt], cb[nxt], out_h, out_c, t == T - 1);
    if (cvtOut)
      gemm64_mfma<<<NBL, 256, 0, stream>>>(hb[nxt], H, outWbL, H, outWbL, H, H, outb, nullptr, out_lp + (size_t)t * V, (size_t)T * V, H, 1, pmvL, plvL);
    else
      gemm64_mfma<<<NBL, 256, 0, stream>>>(hb[nxt], H, outW, H, outW, H, H, outb, nullptr, out_lp + (size_t)t * V, (size_t)T * V, H, 0, pmvL, plvL);
    k_norm_leg<<<64 * 125, 256, 0, stream>>>(pmvL, plvL, out_lp, t);
  }
}